// Round 8
// baseline (139.573 us; speedup 1.0000x reference)
//
#include <hip/hip_runtime.h>

#define Bn 32
#define Cn 64
#define Hn 56
#define Wn 56
#define REPN 50
#define NKn 17
#define HWn (Hn*Wn)           // 3136
#define NSTATf 100352.0f      // B*H*W
#define EPSf 1e-5f

// ws layout (floats) — every slot written unconditionally before any read
#define PART_OFF 0            // [q(6)][r(50)][b(32)] = 9600
#define WEFF_OFF 9600         // [r(50)][t(7)][9] = 3150

#define SEGH 7
#define NTASK 112             // 8 row-segments * 14 quad-cols

// ---------------------------------------------------------------- K0: weights
__global__ void k_weff(const float* __restrict__ w0, const float* __restrict__ w1,
                       const int* __restrict__ Mh, const int* __restrict__ Mv,
                       const int* __restrict__ Mid, float* __restrict__ ws)
{
    int idx = blockIdx.x * blockDim.x + threadIdx.x;
    if (idx >= REPN*63) return;
    int r   = idx / 63;
    int rem = idx % 63;
    int t   = rem / 9;
    int ij  = rem % 9;
    const int* M = (t < 3) ? (Mh + (t*REPN + r)*NKn)
                 : (t < 6) ? (Mv + ((t-3)*REPN + r)*NKn)
                           : (Mid + r*NKn);
    float acc = 0.f;
    #pragma unroll
    for (int k = 0; k < NKn; ++k)
        acc += (float)M[k] * (w0[(r*NKn + k)*9 + ij] + w1[(r*NKn + k)*9 + ij]);
    ws[WEFF_OFF + idx] = acc;
}

// Load input row `row` of channel ch as window X[0..7] = cols 4q-3..4q+4
// (zeros outside [0,56)). Also c55 = input[row][55] for q==0 lanes.
__device__ __forceinline__ void load_row8c(const float* __restrict__ ch, int row, int q,
                                           float* __restrict__ X, float& c55)
{
    bool rv = (row >= 0) && (row < Hn);
    int rc = rv ? row : 0;
    const float* rp = ch + rc*Wn;
    float4 c0 = *(const float4*)(rp + (q ? 4*q - 4 : 0));   // cols 4q-4..4q-1
    float4 c1 = *(const float4*)(rp + 4*q);                 // cols 4q..4q+3
    int ox = (4*q + 4 <= 55) ? 4*q + 4 : 55;                // clamp in-row
    float cx = rp[ox];
    float mr = rv ? 1.f : 0.f;
    float m0 = (rv && q > 0)  ? 1.f : 0.f;
    float mx = (rv && q < 13) ? 1.f : 0.f;
    X[0]=c0.y*m0; X[1]=c0.z*m0; X[2]=c0.w*m0;
    X[3]=c1.x*mr; X[4]=c1.y*mr; X[5]=c1.z*mr; X[6]=c1.w*mr;
    X[7]=cx*mx;
    c55 = (q == 0) ? rp[55]*mr : 0.f;
}

// ---------------------------------------------------- register-walk conv core
// Task tid (<112): quad-col q (0..13), row segment seg (0..7), output rows
// h0..h0+6, pixels (h, 4q..4q+3). Rolling window W[k] = input row h-3+k,
// 8 floats = cols 4q-3..4q+4. C[k] = input[h-3+k][55] (q==0 lanes only).
//  pos0 = conv(h+1,w+1): rows W[2+i], cols X[p+2+j]   (l1,l2,sm)
//  posA = conv(h, w-1|57): rows W[1+i], cols X[p+j]   (l1,l2); w==0 wrap +C
//  posB = conv(h-1|57, w): rows W[i], cols X[p+1+j]   (l1,l2); h==0 wrap +T
// res[p] = input[h][4q+p] = W[3][3+p] — the residual, free.
template <typename F>
__device__ __forceinline__ void conv_walk(const float* __restrict__ ch,
        const float (&wk)[63], int tid, F emit)
{
    if (tid >= NTASK) return;
    int seg = tid / 14;
    int q   = tid - seg*14;
    int h0  = seg * SEGH;
    bool top = (seg == 0);

    float W[5][8], C[5], T[8];
    {
        float dummy;
        if (top) load_row8c(ch, 55, q, T, dummy);
    }
    #pragma unroll
    for (int k = 0; k < 5; ++k)
        load_row8c(ch, h0 - 3 + k, q, W[k], C[k]);

    #pragma unroll
    for (int s = 0; s < SEGH; ++s) {
        int h = h0 + s;
        float Wn8[8], Cn1;
        load_row8c(ch, h + 2, q, Wn8, Cn1);   // prefetch next row

        float l1[4], l2[4], sm[4];
        #pragma unroll
        for (int p = 0; p < 4; ++p) { l1[p]=0.f; l2[p]=0.f; sm[p]=0.f; }
        #pragma unroll
        for (int i = 0; i < 3; ++i)
            #pragma unroll
            for (int j = 0; j < 3; ++j) {
                float wh0 = wk[i*3+j],    wv0 = wk[27+i*3+j], wid = wk[54+i*3+j];
                float wh1 = wk[9+i*3+j],  wv2 = wk[45+i*3+j];
                float wh2 = wk[18+i*3+j], wv1 = wk[36+i*3+j];
                #pragma unroll
                for (int p = 0; p < 4; ++p) {
                    float a  = W[2+i][p+2+j];     // pos0
                    l1[p] = fmaf(a, wh0, l1[p]);
                    l2[p] = fmaf(a, wv0, l2[p]);
                    sm[p] = fmaf(a, wid, sm[p]);
                    float bA = W[1+i][p+j];       // posA
                    l1[p] = fmaf(bA, wh1, l1[p]);
                    l2[p] = fmaf(bA, wv2, l2[p]);
                    float bB = W[i][p+1+j];       // posB
                    l1[p] = fmaf(bB, wh2, l1[p]);
                    l2[p] = fmaf(bB, wv1, l2[p]);
                }
            }
        if (q == 0) {   // col wrap, pixel 0 only
            #pragma unroll
            for (int i = 0; i < 3; ++i) {
                l1[0] = fmaf(C[1+i], wk[9+3*i],  l1[0]);
                l2[0] = fmaf(C[1+i], wk[45+3*i], l2[0]);
            }
        }
        if (s == 0 && top) {   // row wrap, h==0 only
            #pragma unroll
            for (int j = 0; j < 3; ++j)
                #pragma unroll
                for (int p = 0; p < 4; ++p) {
                    l1[p] = fmaf(T[p+1+j], wk[18+j], l1[p]);
                    l2[p] = fmaf(T[p+1+j], wk[36+j], l2[p]);
                }
        }
        float res[4] = {W[3][3], W[3][4], W[3][5], W[3][6]};
        emit(h, q, l1, l2, sm, res);

        #pragma unroll
        for (int k = 0; k < 4; ++k) {
            #pragma unroll
            for (int x = 0; x < 8; ++x) W[k][x] = W[k+1][x];
            C[k] = C[k+1];
        }
        #pragma unroll
        for (int x = 0; x < 8; ++x) W[4][x] = Wn8[x];
        C[4] = Cn1;
    }
}

// ------------- K1: stats (2 channels per block) + ghost copies (2 per block)
// grid = 1024: blocks 0..799 -> stats for (b,r) pairs v=2*bid, 2*bid+1;
//              blocks 800..1023 -> ghost copies, tasks t=2*(bid-800), +1 (448).
__global__ void __launch_bounds__(128) k_stats(const float* __restrict__ in,
        const int* __restrict__ rep_idx, const int* __restrict__ ghost_idx,
        float* __restrict__ ws, float* __restrict__ out)
{
    int bid = blockIdx.x;
    int tid = threadIdx.x;

    if (bid >= 800) {                            // ghost copies
        for (int it = 0; it < 2; ++it) {
            int t = (bid - 800)*2 + it;          // 0..447
            int g = t % 14;
            int b = t / 14;
            int cin = ghost_idx[g];
            const float4* s4 = (const float4*)(in + ((size_t)(b*Cn + cin))*HWn);
            float4* d4 = (float4*)(out + ((size_t)(b*Cn + REPN + g))*HWn);
            for (int i = tid; i < HWn/4; i += 128) d4[i] = s4[i];
        }
        return;
    }

    __shared__ float red[2][6];
    for (int it = 0; it < 2; ++it) {
        int v = bid*2 + it;                      // 0..1599
        int r = v % REPN;
        int b = v / REPN;

        const float* wr = ws + WEFF_OFF + r*63;  // block-uniform -> SGPRs
        float wk[63];
        #pragma unroll
        for (int i = 0; i < 63; ++i) wk[i] = wr[i];
        const float* ch = in + ((size_t)(b*Cn + rep_idx[r]))*HWn;

        float s1=0.f,q1=0.f,s2=0.f,q2=0.f,s3=0.f,q3=0.f;
        conv_walk(ch, wk, tid,
            [&](int h, int q, float* l1, float* l2, float* sm, float* res) {
                (void)h; (void)q; (void)res;
                #pragma unroll
                for (int p = 0; p < 4; ++p) {
                    s1 += l1[p]; q1 += l1[p]*l1[p];
                    s2 += l2[p]; q2 += l2[p]*l2[p];
                    s3 += sm[p]; q3 += sm[p]*sm[p];
                }
            });

        __syncthreads();                         // red[] reuse safe
        {
            float vals[6] = {s1,q1,s2,q2,s3,q3};
            int lane = tid & 63, wave = tid >> 6;
            #pragma unroll
            for (int x = 0; x < 6; ++x) {
                float y = vals[x];
                for (int o = 32; o; o >>= 1) y += __shfl_down(y, o, 64);
                if (lane == 0) red[wave][x] = y;
            }
        }
        __syncthreads();
        if (tid < 6)
            ws[PART_OFF + (tid*REPN + r)*Bn + b] = red[0][tid] + red[1][tid];
    }
}

// ----------------- K2: finalize BN + recompute conv + write (2 ch per block)
// grid = 800: (b,r) pairs v=2*bid, 2*bid+1.
__global__ void __launch_bounds__(128) k_out(const float* __restrict__ in,
        const int* __restrict__ rep_idx, const float* __restrict__ ws,
        float* __restrict__ out)
{
    int bid = blockIdx.x;
    int tid = threadIdx.x;

    __shared__ float sred[6];
    for (int it = 0; it < 2; ++it) {
        int v = bid*2 + it;                      // 0..1599
        int r = v % REPN;
        int b = v / REPN;

        __syncthreads();                         // sred[] reuse safe
        if (tid < 6) {
            const float* pp = ws + PART_OFF + (tid*REPN + r)*Bn;
            float s = 0.f;
            #pragma unroll
            for (int i = 0; i < Bn; ++i) s += pp[i];
            sred[tid] = s;
        }
        __syncthreads();
        const float inv = 1.0f / NSTATf;
        float m1 = sred[0]*inv, v1 = sred[1]*inv - m1*m1;
        float m2 = sred[2]*inv, v2 = sred[3]*inv - m2*m2;
        float m3 = sred[4]*inv, v3 = sred[5]*inv - m3*m3;
        float r1 = rsqrtf(v1 + EPSf), r2 = rsqrtf(v2 + EPSf), r3 = rsqrtf(v3 + EPSf);

        const float* wr = ws + WEFF_OFF + r*63;
        float wk[63];
        #pragma unroll
        for (int i = 0; i < 63; ++i) wk[i] = wr[i];
        const float* ch = in + ((size_t)(b*Cn + rep_idx[r]))*HWn;
        float* dst = out + ((size_t)(b*Cn + r))*HWn;

        conv_walk(ch, wk, tid,
            [&](int h, int q, float* l1, float* l2, float* sm, float* res) {
                float4 o;
                o.x = (l1[0]-m1)*r1 + (l2[0]-m2)*r2 + (sm[0]-m3)*r3 + res[0];
                o.y = (l1[1]-m1)*r1 + (l2[1]-m2)*r2 + (sm[1]-m3)*r3 + res[1];
                o.z = (l1[2]-m1)*r1 + (l2[2]-m2)*r2 + (sm[2]-m3)*r3 + res[2];
                o.w = (l1[3]-m1)*r1 + (l2[3]-m2)*r2 + (sm[3]-m3)*r3 + res[3];
                *(float4*)(dst + h*Wn + 4*q) = o;
            });
    }
}

extern "C" void kernel_launch(void* const* d_in, const int* in_sizes, int n_in,
                              void* d_out, int out_size, void* d_ws, size_t ws_size,
                              hipStream_t stream) {
    const float* in   = (const float*)d_in[0];
    const float* w0   = (const float*)d_in[1];
    const float* w1   = (const float*)d_in[2];
    const int*   Mh   = (const int*)d_in[3];
    const int*   Mv   = (const int*)d_in[4];
    const int*   Mid  = (const int*)d_in[5];
    const int*   ghost= (const int*)d_in[6];
    const int*   rep  = (const int*)d_in[7];
    float* out  = (float*)d_out;
    float* ws   = (float*)d_ws;

    k_weff<<<(REPN*63 + 127)/128, 128, 0, stream>>>(w0, w1, Mh, Mv, Mid, ws);
    k_stats<<<1024, 128, 0, stream>>>(in, rep, ghost, ws, out);
    k_out<<<800, 128, 0, stream>>>(in, rep, ws, out);
}

// Round 9
// 129.112 us; speedup vs baseline: 1.0810x; 1.0810x over previous
//
#include <hip/hip_runtime.h>

#define Bn 32
#define Cn 64
#define Hn 56
#define Wn 56
#define REPN 50
#define NKn 17
#define HWn (Hn*Wn)           // 3136
#define NSTATf 100352.0f      // B*H*W
#define EPSf 1e-5f

// ws layout (floats) — every slot written unconditionally before any read
#define PART_OFF 0            // [q(6)][r(50)][b(32)] = 9600
#define WEFF_OFF 9600         // [r(50)][t(7)][9] = 3150

#define SEGH 4
#define NSEG 14               // 14*4 = 56 rows
#define NTASK (NSEG*14)       // 196 tasks per channel (block = 256 threads)

// ------------------------------------------------------------ weff compute
// wk[t*9+ij] = sum_k M_t[r][k] * (w0[(r*17+k)*9+ij] + w1[...]),
// t: 0..2 Mh (lora1), 3..5 Mv (lora2), 6 Mid (small).
__device__ __forceinline__ float weff_one(int r, int rem,
        const float* __restrict__ w0, const float* __restrict__ w1,
        const int* __restrict__ Mh, const int* __restrict__ Mv,
        const int* __restrict__ Mid)
{
    int t   = rem / 9;
    int ij  = rem % 9;
    const int* M = (t < 3) ? (Mh + (t*REPN + r)*NKn)
                 : (t < 6) ? (Mv + ((t-3)*REPN + r)*NKn)
                           : (Mid + r*NKn);
    float acc = 0.f;
    #pragma unroll
    for (int k = 0; k < NKn; ++k)
        acc += (float)M[k] * (w0[(r*NKn + k)*9 + ij] + w1[(r*NKn + k)*9 + ij]);
    return acc;
}

// Load input row `row` of channel ch as window X[0..7] = cols 4q-3..4q+4
// (zeros outside [0,56)). Also c55 = input[row][55] for q==0 lanes.
__device__ __forceinline__ void load_row8c(const float* __restrict__ ch, int row, int q,
                                           float* __restrict__ X, float& c55)
{
    bool rv = (row >= 0) && (row < Hn);
    int rc = rv ? row : 0;
    const float* rp = ch + rc*Wn;
    float4 c0 = *(const float4*)(rp + (q ? 4*q - 4 : 0));   // cols 4q-4..4q-1
    float4 c1 = *(const float4*)(rp + 4*q);                 // cols 4q..4q+3
    int ox = (4*q + 4 <= 55) ? 4*q + 4 : 55;                // clamp in-row
    float cx = rp[ox];
    float mr = rv ? 1.f : 0.f;
    float m0 = (rv && q > 0)  ? 1.f : 0.f;
    float mx = (rv && q < 13) ? 1.f : 0.f;
    X[0]=c0.y*m0; X[1]=c0.z*m0; X[2]=c0.w*m0;
    X[3]=c1.x*mr; X[4]=c1.y*mr; X[5]=c1.z*mr; X[6]=c1.w*mr;
    X[7]=cx*mx;
    c55 = (q == 0) ? rp[55]*mr : 0.f;
}

// ---------------------------------------------------- register-walk conv core
// Task tid (<196): quad-col q (0..13), row segment seg (0..13), output rows
// h0..h0+3, pixels (h, 4q..4q+3). Rolling window W[k] = input row h-3+k,
// 8 floats = cols 4q-3..4q+4. C[k] = input[h-3+k][55] (q==0 lanes only).
//  pos0 = conv(h+1,w+1): rows W[2+i], cols X[p+2+j]   (l1,l2,sm)
//  posA = conv(h, w-1|57): rows W[1+i], cols X[p+j]   (l1,l2); w==0 wrap +C
//  posB = conv(h-1|57, w): rows W[i], cols X[p+1+j]   (l1,l2); h==0 wrap +T
// res[p] = input[h][4q+p] = W[3][3+p] — the residual, free.
template <typename F>
__device__ __forceinline__ void conv_walk(const float* __restrict__ ch,
        const float (&wk)[63], int tid, F emit)
{
    if (tid >= NTASK) return;
    int seg = tid / 14;
    int q   = tid - seg*14;
    int h0  = seg * SEGH;
    bool top = (seg == 0);

    float W[5][8], C[5], T[8];
    {
        float dummy;
        if (top) load_row8c(ch, 55, q, T, dummy);
    }
    #pragma unroll
    for (int k = 0; k < 5; ++k)
        load_row8c(ch, h0 - 3 + k, q, W[k], C[k]);

    #pragma unroll
    for (int s = 0; s < SEGH; ++s) {
        int h = h0 + s;
        float Wn8[8], Cn1;
        load_row8c(ch, h + 2, q, Wn8, Cn1);   // prefetch next row

        float l1[4], l2[4], sm[4];
        #pragma unroll
        for (int p = 0; p < 4; ++p) { l1[p]=0.f; l2[p]=0.f; sm[p]=0.f; }
        #pragma unroll
        for (int i = 0; i < 3; ++i)
            #pragma unroll
            for (int j = 0; j < 3; ++j) {
                float wh0 = wk[i*3+j],    wv0 = wk[27+i*3+j], wid = wk[54+i*3+j];
                float wh1 = wk[9+i*3+j],  wv2 = wk[45+i*3+j];
                float wh2 = wk[18+i*3+j], wv1 = wk[36+i*3+j];
                #pragma unroll
                for (int p = 0; p < 4; ++p) {
                    float a  = W[2+i][p+2+j];     // pos0
                    l1[p] = fmaf(a, wh0, l1[p]);
                    l2[p] = fmaf(a, wv0, l2[p]);
                    sm[p] = fmaf(a, wid, sm[p]);
                    float bA = W[1+i][p+j];       // posA
                    l1[p] = fmaf(bA, wh1, l1[p]);
                    l2[p] = fmaf(bA, wv2, l2[p]);
                    float bB = W[i][p+1+j];       // posB
                    l1[p] = fmaf(bB, wh2, l1[p]);
                    l2[p] = fmaf(bB, wv1, l2[p]);
                }
            }
        if (q == 0) {   // col wrap, pixel 0 only
            #pragma unroll
            for (int i = 0; i < 3; ++i) {
                l1[0] = fmaf(C[1+i], wk[9+3*i],  l1[0]);
                l2[0] = fmaf(C[1+i], wk[45+3*i], l2[0]);
            }
        }
        if (s == 0 && top) {   // row wrap, h==0 only
            #pragma unroll
            for (int j = 0; j < 3; ++j)
                #pragma unroll
                for (int p = 0; p < 4; ++p) {
                    l1[p] = fmaf(T[p+1+j], wk[18+j], l1[p]);
                    l2[p] = fmaf(T[p+1+j], wk[36+j], l2[p]);
                }
        }
        float res[4] = {W[3][3], W[3][4], W[3][5], W[3][6]};
        emit(h, q, l1, l2, sm, res);

        #pragma unroll
        for (int k = 0; k < 4; ++k) {
            #pragma unroll
            for (int x = 0; x < 8; ++x) W[k][x] = W[k+1][x];
            C[k] = C[k+1];
        }
        #pragma unroll
        for (int x = 0; x < 8; ++x) W[4][x] = Wn8[x];
        C[4] = Cn1;
    }
}

// ----------------- K1: weff (in-block) + stats partials. grid 1600 x 256 thr
__global__ void __launch_bounds__(256) k_stats(const float* __restrict__ in,
        const float* __restrict__ w0, const float* __restrict__ w1,
        const int* __restrict__ Mh, const int* __restrict__ Mv,
        const int* __restrict__ Mid, const int* __restrict__ rep_idx,
        float* __restrict__ ws)
{
    int bid = blockIdx.x;
    int r = bid % REPN;
    int b = bid / REPN;
    int tid = threadIdx.x;

    __shared__ float wkl[63];
    if (tid < 63) {
        float v = weff_one(r, tid, w0, w1, Mh, Mv, Mid);
        wkl[tid] = v;
        if (bid < REPN) ws[WEFF_OFF + bid*63 + tid] = v;  // bid==r here
    }
    __syncthreads();
    float wk[63];
    #pragma unroll
    for (int i = 0; i < 63; ++i) wk[i] = wkl[i];

    const float* ch = in + ((size_t)(b*Cn + rep_idx[r]))*HWn;

    float s1=0.f,q1=0.f,s2=0.f,q2=0.f,s3=0.f,q3=0.f;
    conv_walk(ch, wk, tid,
        [&](int h, int q, float* l1, float* l2, float* sm, float* res) {
            (void)h; (void)q; (void)res;
            #pragma unroll
            for (int p = 0; p < 4; ++p) {
                s1 += l1[p]; q1 += l1[p]*l1[p];
                s2 += l2[p]; q2 += l2[p]*l2[p];
                s3 += sm[p]; q3 += sm[p]*sm[p];
            }
        });

    __shared__ float red[4][6];
    {
        float vals[6] = {s1,q1,s2,q2,s3,q3};
        int lane = tid & 63, wave = tid >> 6;
        #pragma unroll
        for (int v = 0; v < 6; ++v) {
            float x = vals[v];
            for (int o = 32; o; o >>= 1) x += __shfl_down(x, o, 64);
            if (lane == 0) red[wave][v] = x;
        }
    }
    __syncthreads();
    if (tid < 6)
        ws[PART_OFF + (tid*REPN + r)*Bn + b] =
            red[0][tid] + red[1][tid] + red[2][tid] + red[3][tid];
}

// --------- K2: finalize BN + recompute conv + write. grid 2048 x 256 thr
__global__ void __launch_bounds__(256) k_out(const float* __restrict__ in,
        const int* __restrict__ rep_idx, const int* __restrict__ ghost_idx,
        const float* __restrict__ ws, float* __restrict__ out)
{
    int bid = blockIdx.x;
    int c = bid % Cn;
    int b = bid / Cn;
    int tid = threadIdx.x;

    if (c >= REPN) {                             // ghost channel copy
        int cin = ghost_idx[c - REPN];
        const float4* s4 = (const float4*)(in + ((size_t)(b*Cn + cin))*HWn);
        float4* d4 = (float4*)(out + ((size_t)(b*Cn + c))*HWn);
        for (int i = tid; i < HWn/4; i += 256) d4[i] = s4[i];
        return;
    }

    int r = c;
    __shared__ float sred[6];
    if (tid < 6) {
        const float* pp = ws + PART_OFF + (tid*REPN + r)*Bn;
        float s = 0.f;
        #pragma unroll
        for (int i = 0; i < Bn; ++i) s += pp[i];
        sred[tid] = s;
    }
    __syncthreads();
    const float inv = 1.0f / NSTATf;
    float m1 = sred[0]*inv, v1 = sred[1]*inv - m1*m1;
    float m2 = sred[2]*inv, v2 = sred[3]*inv - m2*m2;
    float m3 = sred[4]*inv, v3 = sred[5]*inv - m3*m3;
    float r1 = rsqrtf(v1 + EPSf), r2 = rsqrtf(v2 + EPSf), r3 = rsqrtf(v3 + EPSf);

    const float* wr = ws + WEFF_OFF + r*63;      // block-uniform -> s_load
    float wk[63];
    #pragma unroll
    for (int i = 0; i < 63; ++i) wk[i] = wr[i];

    const float* ch = in + ((size_t)(b*Cn + rep_idx[r]))*HWn;
    float* dst = out + ((size_t)(b*Cn + c))*HWn;

    conv_walk(ch, wk, tid,
        [&](int h, int q, float* l1, float* l2, float* sm, float* res) {
            float4 o;
            o.x = (l1[0]-m1)*r1 + (l2[0]-m2)*r2 + (sm[0]-m3)*r3 + res[0];
            o.y = (l1[1]-m1)*r1 + (l2[1]-m2)*r2 + (sm[1]-m3)*r3 + res[1];
            o.z = (l1[2]-m1)*r1 + (l2[2]-m2)*r2 + (sm[2]-m3)*r3 + res[2];
            o.w = (l1[3]-m1)*r1 + (l2[3]-m2)*r2 + (sm[3]-m3)*r3 + res[3];
            *(float4*)(dst + h*Wn + 4*q) = o;
        });
}

extern "C" void kernel_launch(void* const* d_in, const int* in_sizes, int n_in,
                              void* d_out, int out_size, void* d_ws, size_t ws_size,
                              hipStream_t stream) {
    const float* in   = (const float*)d_in[0];
    const float* w0   = (const float*)d_in[1];
    const float* w1   = (const float*)d_in[2];
    const int*   Mh   = (const int*)d_in[3];
    const int*   Mv   = (const int*)d_in[4];
    const int*   Mid  = (const int*)d_in[5];
    const int*   ghost= (const int*)d_in[6];
    const int*   rep  = (const int*)d_in[7];
    float* out  = (float*)d_out;
    float* ws   = (float*)d_ws;

    k_stats<<<Bn*REPN, 256, 0, stream>>>(in, w0, w1, Mh, Mv, Mid, rep, ws);
    k_out<<<Bn*Cn, 256, 0, stream>>>(in, rep, ghost, ws, out);
}